// Round 5
// baseline (230.487 us; speedup 1.0000x reference)
//
#include <hip/hip_runtime.h>
#include <hip/hip_bf16.h>
#include <stdint.h>

// Problem constants
#define BB 8
#define SS 2048
#define NEXP 16
#define DIN 1024
#define DOUT 1024

typedef short bf16x8 __attribute__((ext_vector_type(8)));
typedef float floatx4 __attribute__((ext_vector_type(4)));

// fp32 -> bf16 round-to-nearest-even (bit trick; inputs are normal floats)
__device__ __forceinline__ unsigned short f2bf(float f) {
    union { float f; unsigned int u; } v; v.f = f;
    unsigned int u = v.u;
    unsigned int r = u + 0x7FFFu + ((u >> 16) & 1u);
    return (unsigned short)(r >> 16);
}

// 2x fp32 -> packed bf16x2 (hardware v_cvt_pk_bf16_f32, RNE)
__device__ __forceinline__ unsigned pk2(float a, float b) {
    __hip_bfloat162 h = __float22bfloat162_rn(float2{a, b});
    union { __hip_bfloat162 h; unsigned u; } cv; cv.h = h;
    return cv.u;
}

// async global->LDS, 16B per lane. LDS dest = wave-uniform base + lane*16.
__device__ __forceinline__ void gload16(const void* g, void* l) {
    __builtin_amdgcn_global_load_lds(
        (const __attribute__((address_space(1))) void*)g,
        (__attribute__((address_space(3))) void*)l,
        16, 0, 0);
}

// ---------------------------------------------------------------------------
// Kernel 1 (prep): wmix + bias only (~15 us). xconv fused into gemm (R6).
// ---------------------------------------------------------------------------
__global__ __launch_bounds__(256) void prep_kernel(
    const float* __restrict__ p, const float* __restrict__ w,
    const float* __restrict__ bias,
    unsigned short* __restrict__ mw, float* __restrict__ mb)
{
    const int tid = threadIdx.x;
    const int blk = blockIdx.x;

    if (blk < 2048) {                       // ---- weight mix ----
        __shared__ float sp[BB * NEXP];
        if (tid < BB * NEXP) sp[tid] = p[tid];
        __syncthreads();
        const long t  = (long)blk * 256 + tid;      // 0..524287
        const long j2 = t * 2;                      // column pair
        float acc[BB][2];
        #pragma unroll
        for (int b = 0; b < BB; ++b) { acc[b][0] = 0.f; acc[b][1] = 0.f; }
        #pragma unroll
        for (int n = 0; n < NEXP; ++n) {
            float2 wv = *(const float2*)(w + (long)n * DOUT * DIN + j2);
            #pragma unroll
            for (int b = 0; b < BB; ++b) {
                float pb = sp[b * NEXP + n];
                acc[b][0] += pb * wv.x; acc[b][1] += pb * wv.y;
            }
        }
        #pragma unroll
        for (int b = 0; b < BB; ++b) {
            unsigned o = (unsigned)f2bf(acc[b][0]) | ((unsigned)f2bf(acc[b][1]) << 16);
            *(unsigned*)(mw + (long)b * DOUT * DIN + j2) = o;
        }
    } else {                                // ---- bias mix (tiny) ----
        const long t = (long)(blk - 2048) * 256 + tid;    // 0..8191
        const int b = (int)(t >> 10), i = (int)(t & 1023);
        float s = 0.f;
        #pragma unroll
        for (int n = 0; n < NEXP; ++n) s += p[b * NEXP + n] * bias[n * DOUT + i];
        mb[t] = s;
    }
}

// ---------------------------------------------------------------------------
// Kernel 2: batched GEMM  out[b] = cvt_bf16(x[b]) (S x K) * mixed_w[b]^T + mb[b]
// R8: full 1-deep software pipeline. R7 post-mortem: vmcnt(8) hid A's latency
// but B(t) was still issued AND waited within the same iteration (~300-500 cy
// exposed per K-step; MfmaUtil 15.6%). Fix: DOUBLE-BUFFER sB so B(t+1) is
// issued one iteration early, alongside the A(t+1) reg-prefetch.
// Steady-state iteration t:
//   lgkmcnt(0); s_barrier            // sync1: all waves consumed sA / sB[t-1&1]
//   cvt A(t) regs -> sA              // compiler inserts vmcnt(0) here; it
//                                    //   retires B(t) too (FIFO, A is newest)
//                                    //   — both issued LAST iter => hidden
//   issue B(t+1) -> sB[(t+1)&1]      // async gload_lds, flies under MFMA
//   issue A(t+1) -> regs             // flies under MFMA
//   lgkmcnt(0); s_barrier            // sync2: ds_writes visible
//   ds_read + 32 MFMA  (sA, sB[t&1])
// No hand-counted vmcnt left. Exposed VMEM latency: t=0 prologue only.
// LDS 48 KB -> 3 blocks/CU (12 waves). Buffer indices (t&1) are compile-time
// (full unroll) — no runtime-indexed LDS arrays (rule #20).
// ---------------------------------------------------------------------------
__global__ __launch_bounds__(256) void gemm_kernel(
    const float* __restrict__ x,             // [B][S][DIN] fp32
    const unsigned short* __restrict__ mw,   // [B][DOUT][DIN] bf16
    const float* __restrict__ mb,            // [B][DOUT] fp32
    float* __restrict__ out)                 // [B][S][DOUT] fp32
{
    __shared__ __align__(16) unsigned short sA[128 * 64];       // 16 KB
    __shared__ __align__(16) unsigned short sB[2][128 * 64];    // 32 KB

    const int tid  = threadIdx.x;
    const int wave = tid >> 6;
    const int lane = tid & 63;
    const int b    = blockIdx.x;          // batch -> XCD (id % 8 == b)
    const int tileN = blockIdx.y * 128;   // over DOUT
    const int tileM = blockIdx.z * 128;   // over S

    const float*          Ag = x  + (long)b * SS * DIN;
    const unsigned short* Bg = mw + (long)b * DOUT * DIN;

    const int q     = lane >> 4;     // quad 0..3
    const int r16   = lane & 15;
    const int mBase = 64 * (wave >> 1);
    const int nBase = 64 * (wave & 1);

    // staging: each wave owns 4 chunks of 8 rows x 64 cols for A and B
    const int sRow   = lane >> 3;                    // 0..7 row within chunk
    const int sColSw = (((lane & 7) ^ sRow) * 8);    // XOR-swizzled source column
    const int chunkBase = wave * 4;

    const float* aSrc[4]; const unsigned short* bSrc[4];
    unsigned short* aDst[4];
    #pragma unroll
    for (int c = 0; c < 4; ++c) {
        const int chunk = chunkBase + c;             // 0..15
        const int row   = chunk * 8 + sRow;          // 0..127
        aSrc[c] = Ag + (long)(tileM + row) * DIN + sColSw;
        bSrc[c] = Bg + (long)(tileN + row) * DIN + sColSw;
        aDst[c] = &sA[chunk * 512 + lane * 8];       // explicit per-lane 16B slot
    }

    // reader: XOR-swizzled 16B-group offsets for the two kk halves (invariant)
    const int swz  = r16 & 7;
    const int colK0 = ((q)     ^ swz) * 8;           // kk = 0..31  (group q)
    const int colK1 = ((q + 4) ^ swz) * 8;           // kk = 32..63 (group q+4)

    floatx4 acc[4][4];
    #pragma unroll
    for (int mi = 0; mi < 4; ++mi)
        #pragma unroll
        for (int ni = 0; ni < 4; ++ni)
            acc[mi][ni] = (floatx4){0.f, 0.f, 0.f, 0.f};

    // prologue: B(0) -> sB[0] (async), A(0) -> regs
    #pragma unroll
    for (int c = 0; c < 4; ++c)
        gload16(bSrc[c], &sB[0][(chunkBase + c) * 512]);
    float4 aReg[4][2];
    #pragma unroll
    for (int c = 0; c < 4; ++c) {
        aReg[c][0] = *(const float4*)(aSrc[c]);
        aReg[c][1] = *(const float4*)(aSrc[c] + 4);
    }

    #pragma unroll
    for (int t = 0; t < 16; ++t) {
        // sync1: all waves done consuming sA and sB[(t-1)&1]
        asm volatile("s_waitcnt lgkmcnt(0)" ::: "memory");
        __builtin_amdgcn_s_barrier();

        // A(t): cvt from regs -> sA. Compiler's vmcnt wait here retires
        // A(t) AND B(t) (both issued last iteration -> latency hidden).
        #pragma unroll
        for (int c = 0; c < 4; ++c) {
            float4 u = aReg[c][0], v = aReg[c][1];
            uint4 o;
            o.x = pk2(u.x, u.y); o.y = pk2(u.z, u.w);
            o.z = pk2(v.x, v.y); o.w = pk2(v.z, v.w);
            *(uint4*)aDst[c] = o;
        }

        // prefetch next tile: B(t+1) async to alternate buffer, A(t+1) to regs
        if (t < 15) {
            #pragma unroll
            for (int c = 0; c < 4; ++c)
                gload16(bSrc[c] + 64 * (t + 1), &sB[(t + 1) & 1][(chunkBase + c) * 512]);
            #pragma unroll
            for (int c = 0; c < 4; ++c) {
                aReg[c][0] = *(const float4*)(aSrc[c] + 64 * (t + 1));
                aReg[c][1] = *(const float4*)(aSrc[c] + 64 * (t + 1) + 4);
            }
        }

        // sync2: own ds_writes visible to all waves
        asm volatile("s_waitcnt lgkmcnt(0)" ::: "memory");
        __builtin_amdgcn_s_barrier();

        #pragma unroll
        for (int kh = 0; kh < 2; ++kh) {
            const int col = kh ? colK1 : colK0;
            bf16x8 af[4], bfv[4];
            #pragma unroll
            for (int i = 0; i < 4; ++i)
                af[i] = *(const bf16x8*)&sA[(mBase + 16 * i + r16) * 64 + col];
            #pragma unroll
            for (int i = 0; i < 4; ++i)
                bfv[i] = *(const bf16x8*)&sB[t & 1][(nBase + 16 * i + r16) * 64 + col];
            #pragma unroll
            for (int mi = 0; mi < 4; ++mi)
                #pragma unroll
                for (int ni = 0; ni < 4; ++ni)
                    acc[mi][ni] = __builtin_amdgcn_mfma_f32_16x16x32_bf16(
                        af[mi], bfv[ni], acc[mi][ni], 0, 0, 0);
        }
    }

    // epilogue: C[m][n] = acc + mixed_b[b][n]
    float bv[4];
    #pragma unroll
    for (int ni = 0; ni < 4; ++ni)
        bv[ni] = mb[b * DOUT + tileN + nBase + 16 * ni + r16];

    #pragma unroll
    for (int mi = 0; mi < 4; ++mi) {
        #pragma unroll
        for (int rr = 0; rr < 4; ++rr) {
            const int row = tileM + mBase + 16 * mi + q * 4 + rr;
            float* orow = out + (long)b * SS * DOUT + (long)row * DOUT;
            #pragma unroll
            for (int ni = 0; ni < 4; ++ni)
                orow[tileN + nBase + 16 * ni + r16] = acc[mi][ni][rr] + bv[ni];
        }
    }
}

extern "C" void kernel_launch(void* const* d_in, const int* in_sizes, int n_in,
                              void* d_out, int out_size, void* d_ws, size_t ws_size,
                              hipStream_t stream) {
    const float* x    = (const float*)d_in[0];   // [8,2048,1024]
    const float* p    = (const float*)d_in[1];   // [8,16]
    const float* w    = (const float*)d_in[2];   // [16,1024,1024]
    const float* bias = (const float*)d_in[3];   // [16,1024]
    float* out = (float*)d_out;                  // [8,2048,1024]

    // workspace layout: mixed_w bf16 (16 MiB) | mixed_b fp32 (32 KiB)
    unsigned short* mw = (unsigned short*)d_ws;
    float*          mb = (float*)((char*)d_ws + (size_t)16777216);

    prep_kernel<<<dim3(2080), 256, 0, stream>>>(p, w, bias, mw, mb);

    dim3 ggrid(BB, DOUT / 128, SS / 128);        // (8,8,16) = 1024 blocks
    gemm_kernel<<<ggrid, 256, 0, stream>>>(x, mw, mb, out);
}

// Round 6
// 212.245 us; speedup vs baseline: 1.0859x; 1.0859x over previous
//
#include <hip/hip_runtime.h>
#include <hip/hip_bf16.h>
#include <stdint.h>

// Problem constants
#define BB 8
#define SS 2048
#define NEXP 16
#define DIN 1024
#define DOUT 1024

typedef short bf16x8 __attribute__((ext_vector_type(8)));
typedef float floatx4 __attribute__((ext_vector_type(4)));

// fp32 -> bf16 round-to-nearest-even (bit trick; inputs are normal floats)
__device__ __forceinline__ unsigned short f2bf(float f) {
    union { float f; unsigned int u; } v; v.f = f;
    unsigned int u = v.u;
    unsigned int r = u + 0x7FFFu + ((u >> 16) & 1u);
    return (unsigned short)(r >> 16);
}

// async global->LDS, 16B per lane. LDS dest = wave-uniform base + lane*16.
__device__ __forceinline__ void gload16(const void* g, void* l) {
    __builtin_amdgcn_global_load_lds(
        (const __attribute__((address_space(1))) void*)g,
        (__attribute__((address_space(3))) void*)l,
        16, 0, 0);
}

// ---------------------------------------------------------------------------
// R9 decomposition: three kernels, each a previously-measured structure.
//   1) prep  (wmix+bias)            ~15 us  (measured via wall algebra R6-R8)
//   2) xconv (pure x fp32->bf16)    ~20 us  (pure stream; escapes the 2.07TB/s
//                                            ceiling of the FUSED xconv+wmix,
//                                            which mixed HBM+L3 read streams)
//   3) gemm  (all-bf16, R0/R5 code) ~47 us  (proven twice)
// R6-R8 fused-A arc reverted: gemm ballooned 48->85-90 us with an
// uncharacterized per-iter stall (MfmaUtil 15%); methodology says revert.
// ---------------------------------------------------------------------------

// Kernel 1: weight mix + bias mix (R6's proven code)
__global__ __launch_bounds__(256) void prep_kernel(
    const float* __restrict__ p, const float* __restrict__ w,
    const float* __restrict__ bias,
    unsigned short* __restrict__ mw, float* __restrict__ mb)
{
    const int tid = threadIdx.x;
    const int blk = blockIdx.x;

    if (blk < 2048) {                       // ---- weight mix ----
        __shared__ float sp[BB * NEXP];
        if (tid < BB * NEXP) sp[tid] = p[tid];
        __syncthreads();
        const long t  = (long)blk * 256 + tid;      // 0..524287
        const long j2 = t * 2;                      // column pair
        float acc[BB][2];
        #pragma unroll
        for (int b = 0; b < BB; ++b) { acc[b][0] = 0.f; acc[b][1] = 0.f; }
        #pragma unroll
        for (int n = 0; n < NEXP; ++n) {
            float2 wv = *(const float2*)(w + (long)n * DOUT * DIN + j2);
            #pragma unroll
            for (int b = 0; b < BB; ++b) {
                float pb = sp[b * NEXP + n];
                acc[b][0] += pb * wv.x; acc[b][1] += pb * wv.y;
            }
        }
        #pragma unroll
        for (int b = 0; b < BB; ++b) {
            unsigned o = (unsigned)f2bf(acc[b][0]) | ((unsigned)f2bf(acc[b][1]) << 16);
            *(unsigned*)(mw + (long)b * DOUT * DIN + j2) = o;
        }
    } else {                                // ---- bias mix (tiny) ----
        const long t = (long)(blk - 2048) * 256 + tid;    // 0..8191
        const int b = (int)(t >> 10), i = (int)(t & 1023);
        float s = 0.f;
        #pragma unroll
        for (int n = 0; n < NEXP; ++n) s += p[b * NEXP + n] * bias[n * DOUT + i];
        mb[t] = s;
    }
}

// Kernel 2: standalone x fp32 -> bf16 stream (96 MB total traffic).
// 4096 blocks x 256 thr x 4 float4; wave reads 1KB / writes 512B contiguous.
__global__ __launch_bounds__(256) void xconv_kernel(
    const float* __restrict__ x, unsigned short* __restrict__ xb)
{
    const float4* xv = (const float4*)x;
    uint2* xo = (uint2*)xb;
    const int base = blockIdx.x * 1024 + threadIdx.x;
    #pragma unroll
    for (int u = 0; u < 4; ++u) {
        float4 v = xv[base + u * 256];
        uint2 o;
        o.x = (unsigned)f2bf(v.x) | ((unsigned)f2bf(v.y) << 16);
        o.y = (unsigned)f2bf(v.z) | ((unsigned)f2bf(v.w) << 16);
        xo[base + u * 256] = o;
    }
}

// ---------------------------------------------------------------------------
// Kernel 3: batched GEMM  out[b] = x_bf16[b] (S x K) * mixed_w[b]^T + mixed_b[b]
// R0/R5 proven structure, verbatim: block-shared gload_lds staging for BOTH
// operands, 2 barriers/iter, fully unrolled K; per-iter offset folds into the
// 13-bit immediate. Grid (B,N,M): id % 8 == b -> per-XCD L2 (FETCH 139->33MB).
// XOR swizzle -> 0 bank conflicts. LDS 32KB -> 4 blocks/CU (16 waves).
// ---------------------------------------------------------------------------
__global__ __launch_bounds__(256) void gemm_kernel(
    const unsigned short* __restrict__ xb,   // [B][S][DIN] bf16
    const unsigned short* __restrict__ mw,   // [B][DOUT][DIN] bf16
    const float* __restrict__ mb,            // [B][DOUT] fp32
    float* __restrict__ out)                 // [B][S][DOUT] fp32
{
    __shared__ __align__(16) unsigned short sA[128 * 64];  // 16 KB
    __shared__ __align__(16) unsigned short sB[128 * 64];  // 16 KB

    const int tid  = threadIdx.x;
    const int wave = tid >> 6;
    const int lane = tid & 63;
    const int b    = blockIdx.x;          // batch -> XCD (id % 8 == b)
    const int tileN = blockIdx.y * 128;   // over DOUT
    const int tileM = blockIdx.z * 128;   // over S

    const unsigned short* Ag = xb + (long)b * SS * DIN;
    const unsigned short* Bg = mw + (long)b * DOUT * DIN;

    const int q     = lane >> 4;     // quad 0..3
    const int r16   = lane & 15;
    const int mBase = 64 * (wave >> 1);
    const int nBase = 64 * (wave & 1);

    // staging: each wave owns 4 chunks of 1KB (8 rows x 64 bf16) for A and B
    const int sRow   = lane >> 3;                    // 0..7 row within chunk
    const int sColSw = (((lane & 7) ^ sRow) * 8);    // XOR-swizzled source column

    // hoisted global source bases + LDS destinations (loop-invariant)
    const unsigned short* aSrc[4]; const unsigned short* bSrc[4];
    unsigned short* aDst[4]; unsigned short* bDst[4];
    #pragma unroll
    for (int c = 0; c < 4; ++c) {
        const int chunk = wave * 4 + c;              // 0..15
        const int row   = chunk * 8 + sRow;          // 0..127
        aSrc[c] = Ag + (long)(tileM + row) * DIN + sColSw;
        bSrc[c] = Bg + (long)(tileN + row) * DIN + sColSw;
        aDst[c] = &sA[chunk * 512];
        bDst[c] = &sB[chunk * 512];
    }

    // reader: XOR-swizzled 16B-group offsets for the two kk halves (invariant)
    const int swz  = r16 & 7;
    const int colK0 = ((q)     ^ swz) * 8;           // kk = 0..31  (group q)
    const int colK1 = ((q + 4) ^ swz) * 8;           // kk = 32..63 (group q+4)

    floatx4 acc[4][4];
    #pragma unroll
    for (int mi = 0; mi < 4; ++mi)
        #pragma unroll
        for (int ni = 0; ni < 4; ++ni)
            acc[mi][ni] = (floatx4){0.f, 0.f, 0.f, 0.f};

    #pragma unroll
    for (int t = 0; t < 16; ++t) {                   // k0 = 64*t, fully unrolled
        __syncthreads();   // previous tile's compute done before overwrite
        #pragma unroll
        for (int c = 0; c < 4; ++c) {
            gload16(aSrc[c] + 64 * t, aDst[c]);      // +128*t bytes -> imm offset
            gload16(bSrc[c] + 64 * t, bDst[c]);
        }
        __syncthreads();   // loads visible

        #pragma unroll
        for (int kh = 0; kh < 2; ++kh) {
            const int col = kh ? colK1 : colK0;
            bf16x8 af[4], bfv[4];
            #pragma unroll
            for (int i = 0; i < 4; ++i)
                af[i] = *(const bf16x8*)&sA[(mBase + 16 * i + r16) * 64 + col];
            #pragma unroll
            for (int i = 0; i < 4; ++i)
                bfv[i] = *(const bf16x8*)&sB[(nBase + 16 * i + r16) * 64 + col];
            #pragma unroll
            for (int mi = 0; mi < 4; ++mi)
                #pragma unroll
                for (int ni = 0; ni < 4; ++ni)
                    acc[mi][ni] = __builtin_amdgcn_mfma_f32_16x16x32_bf16(
                        af[mi], bfv[ni], acc[mi][ni], 0, 0, 0);
        }
    }

    // epilogue: C[m][n] = acc + mixed_b[b][n]
    float bv[4];
    #pragma unroll
    for (int ni = 0; ni < 4; ++ni)
        bv[ni] = mb[b * DOUT + tileN + nBase + 16 * ni + r16];

    #pragma unroll
    for (int mi = 0; mi < 4; ++mi) {
        #pragma unroll
        for (int rr = 0; rr < 4; ++rr) {
            const int row = tileM + mBase + 16 * mi + q * 4 + rr;
            float* orow = out + (long)b * SS * DOUT + (long)row * DOUT;
            #pragma unroll
            for (int ni = 0; ni < 4; ++ni)
                orow[tileN + nBase + 16 * ni + r16] = acc[mi][ni][rr] + bv[ni];
        }
    }
}

extern "C" void kernel_launch(void* const* d_in, const int* in_sizes, int n_in,
                              void* d_out, int out_size, void* d_ws, size_t ws_size,
                              hipStream_t stream) {
    const float* x    = (const float*)d_in[0];   // [8,2048,1024]
    const float* p    = (const float*)d_in[1];   // [8,16]
    const float* w    = (const float*)d_in[2];   // [16,1024,1024]
    const float* bias = (const float*)d_in[3];   // [16,1024]
    float* out = (float*)d_out;                  // [8,2048,1024]

    // workspace layout: x_bf16 (32 MiB) | mixed_w bf16 (16 MiB) | mixed_b fp32 (32 KiB)
    unsigned short* xb = (unsigned short*)d_ws;
    unsigned short* mw = (unsigned short*)((char*)d_ws + (size_t)33554432);
    float*          mb = (float*)((char*)d_ws + (size_t)33554432 + 16777216);

    prep_kernel<<<dim3(2080), 256, 0, stream>>>(p, w, bias, mw, mb);
    xconv_kernel<<<dim3(4096), 256, 0, stream>>>(x, xb);

    dim3 ggrid(BB, DOUT / 128, SS / 128);        // (8,8,16) = 1024 blocks
    gemm_kernel<<<ggrid, 256, 0, stream>>>(xb, mw, mb, out);
}